// Round 5
// baseline (185.729 us; speedup 1.0000x reference)
//
#include <hip/hip_runtime.h>
#include <hip/hip_cooperative_groups.h>
#include <math.h>

namespace cg = cooperative_groups;

#define N_NODES 10000
#define N_EDGES 320000
#define D 256
#define CAP 128   // per-node in-edge cap; deg ~ Poisson(32), P(>128) ~ 0
#define BM 32     // GEMM row-tile
#define LDK 40    // LDS k-stride in ushorts (80 B rows: 16B-aligned, bank-spread)
#define GB_GEMM ((N_NODES + BM - 1) / BM)      // 313 GEMM tile-jobs
#define GB_BUILD ((N_EDGES + 255) / 256)       // 1250 edge-chunk jobs
#define N_AGG (N_NODES / 4)                    // 2500 agg jobs (4 nodes each)

typedef __attribute__((ext_vector_type(8))) short short8;
typedef __attribute__((ext_vector_type(4))) float f32x4;

__device__ __forceinline__ ushort f2bf(float f) {
    union { float f; unsigned u; } v; v.f = f;
    unsigned r = v.u + 0x7FFFu + ((v.u >> 16) & 1u);  // RNE
    return (ushort)(r >> 16);
}
__device__ __forceinline__ float bf2f(ushort u) {
    union { unsigned u; float f; } v; v.u = (unsigned)u << 16;
    return v.f;
}

// One persistent cooperative kernel: phase0 (W->bf16, deg=0) | sync |
// phase1 (GEMM-fused + edge scatter, grid-stride jobs) | sync | phase2 (agg).
__global__ __launch_bounds__(256, 4) void k_all(const float* __restrict__ x,
                                                const int* __restrict__ ei,
                                                const float* __restrict__ W,
                                                const float* __restrict__ b,
                                                const float* __restrict__ mag_w,
                                                const float* __restrict__ mag_b,
                                                const float* __restrict__ attn_w,
                                                unsigned* __restrict__ deg,
                                                int* __restrict__ csr_src,
                                                ushort* __restrict__ hb,
                                                float* __restrict__ es,
                                                ushort* __restrict__ Wb,
                                                float* __restrict__ out) {
    cg::grid_group grid = cg::this_grid();
    const int t = threadIdx.x;
    const int nthread = gridDim.x * 256;

    // ---------------- phase 0: W fp32->bf16 + zero deg ----------------
    for (int tid = blockIdx.x * 256 + t; tid < (D * D) / 4; tid += nthread) {
        const float4 v = *(const float4*)&W[tid * 4];
        ushort4 o;
        o.x = f2bf(v.x); o.y = f2bf(v.y); o.z = f2bf(v.z); o.w = f2bf(v.w);
        *(ushort4*)&Wb[tid * 4] = o;
    }
    for (int tid = blockIdx.x * 256 + t; tid < N_NODES; tid += nthread)
        deg[tid] = 0u;
    grid.sync();

    // ---------------- phase 1: GEMM-fused tiles + edge scatter ----------------
    {
        __shared__ ushort ldsA[BM * LDK];
        __shared__ ushort ldsB[256 * LDK];
        __shared__ float red_ssq[4][BM], red_ra[4][BM];
        __shared__ float smrow[BM], scl[BM];

        const int w = t >> 6, l = t & 63;
        const int sra = t >> 3, ka = (t & 7) * 4;   // A staging: 8 thr/row x 4 floats
        const int srb = t >> 2, kb = (t & 3) * 8;   // B staging: 4 thr/row x 8 bf16
        const int fl = l & 15;
        const int fh = (l >> 4) * 8;
        const int rq = (l >> 4) * 4;

        for (int job = blockIdx.x; job < GB_GEMM + GB_BUILD; job += gridDim.x) {
            if (job >= GB_GEMM) {
                // ---- edge scatter: fixed-stride CSR by target ----
                const int e = (job - GB_GEMM) * 256 + t;
                if (e < N_EDGES) {
                    int src = ei[e];
                    int tgt = ei[N_EDGES + e];
                    src = min(max(src, 0), N_NODES - 1);
                    tgt = min(max(tgt, 0), N_NODES - 1);
                    const unsigned slot = atomicAdd(&deg[tgt], 1u);
                    if (slot < CAP) csr_src[(size_t)tgt * CAP + slot] = src;
                }
                continue;
            }
            // ---- GEMM tile: 32 rows x 256 cols; wave w owns col strip w*64 ----
            const int bm = job * BM;
            const int am = bm + sra;

            f32x4 acc[2][4];
#pragma unroll
            for (int r = 0; r < 2; ++r)
#pragma unroll
                for (int c = 0; c < 4; ++c) acc[r][c] = (f32x4)(0.f);
            float sm_part = 0.f;

            for (int k0 = 0; k0 < D; k0 += 32) {
                float4 xa = make_float4(0.f, 0.f, 0.f, 0.f);
                if (am < N_NODES) xa = *(const float4*)&x[(size_t)am * D + k0 + ka];
                const float4 mwv = *(const float4*)&mag_w[k0 + ka];
                sm_part += xa.x * mwv.x + xa.y * mwv.y + xa.z * mwv.z + xa.w * mwv.w;
                short8 bv[4];
#pragma unroll
                for (int p = 0; p < 4; ++p)
                    bv[p] = *(const short8*)&Wb[(size_t)(p * 64 + srb) * D + k0 + kb];
                __syncthreads();   // previous fragment reads done
                ushort4 av;
                av.x = f2bf(xa.x); av.y = f2bf(xa.y); av.z = f2bf(xa.z); av.w = f2bf(xa.w);
                *(ushort4*)&ldsA[sra * LDK + ka] = av;
#pragma unroll
                for (int p = 0; p < 4; ++p)
                    *(short8*)&ldsB[(p * 64 + srb) * LDK + kb] = bv[p];
                __syncthreads();
                short8 af[2], bfr[4];
#pragma unroll
                for (int r = 0; r < 2; ++r)
                    af[r] = *(short8*)&ldsA[(r * 16 + fl) * LDK + fh];
#pragma unroll
                for (int c = 0; c < 4; ++c)
                    bfr[c] = *(short8*)&ldsB[(w * 64 + c * 16 + fl) * LDK + fh];
#pragma unroll
                for (int r = 0; r < 2; ++r)
#pragma unroll
                    for (int c = 0; c < 4; ++c)
                        acc[r][c] = __builtin_amdgcn_mfma_f32_16x16x32_bf16(af[r], bfr[c], acc[r][c], 0, 0, 0);
            }

            // mag dot: reduce across the 8 staging threads of each row
            float smp = sm_part;
#pragma unroll
            for (int o = 1; o < 8; o <<= 1) smp += __shfl_xor(smp, o);
            if ((t & 7) == 0) smrow[sra] = smp;

            float bn[4], asn[4];
#pragma unroll
            for (int c = 0; c < 4; ++c) {
                const int n = w * 64 + c * 16 + fl;
                bn[c]  = b[n];
                asn[c] = attn_w[n];
            }

            // row reductions (ssq, h.a_s) within wave, then LDS cross-wave
#pragma unroll
            for (int r = 0; r < 2; ++r) {
#pragma unroll
                for (int reg = 0; reg < 4; ++reg) {
                    float vssq = 0.f, vra = 0.f;
#pragma unroll
                    for (int c = 0; c < 4; ++c) {
                        const float v = acc[r][c][reg] + bn[c];
                        vssq += v * v;
                        vra  += v * asn[c];
                    }
#pragma unroll
                    for (int o = 1; o < 16; o <<= 1) {
                        vssq += __shfl_xor(vssq, o);
                        vra  += __shfl_xor(vra, o);
                    }
                    if (fl == 0) {
                        const int m = r * 16 + rq + reg;
                        red_ssq[w][m] = vssq;
                        red_ra[w][m]  = vra;
                    }
                }
            }
            __syncthreads();

            if (t < BM) {
                const int gm = bm + t;
                const float ssq = red_ssq[0][t] + red_ssq[1][t] + red_ssq[2][t] + red_ssq[3][t];
                const float ra  = red_ra[0][t]  + red_ra[1][t]  + red_ra[2][t]  + red_ra[3][t];
                const float norm = sqrtf(ssq);
                const float mag  = 1.5f / (1.f + expf(-(smrow[t] + mag_b[0])));
                const float scale = mag / fmaxf(norm, 1e-12f);
                scl[t] = scale;
                if (gm < N_NODES) es[gm] = expf(ra * scale);   // exp(s_s); |s_s| <= ~1.1
            }
            __syncthreads();

            // write hb = bf16(h_raw * scale)
#pragma unroll
            for (int r = 0; r < 2; ++r) {
#pragma unroll
                for (int reg = 0; reg < 4; ++reg) {
                    const int ml = r * 16 + rq + reg;
                    const int m = bm + ml;
                    if (m < N_NODES) {
                        const float scale = scl[ml];
#pragma unroll
                        for (int c = 0; c < 4; ++c) {
                            const int n = w * 64 + c * 16 + fl;
                            hb[(size_t)m * D + n] = f2bf((acc[r][c][reg] + bn[c]) * scale);
                        }
                    }
                }
            }
        }
    }
    grid.sync();

    // ---------------- phase 2: single-pass weighted gather + expmap0 + clip ----
    // attn = es[src]/Σes[src] (s_t[tgt] cancels in segment softmax; |s_s|<=1.1
    // so the max-shift is unnecessary). 1 wave per node, no LDS/barriers.
    {
        const int wv = threadIdx.x >> 6;
        const int lane = threadIdx.x & 63;
        const int coff = lane * 4;

        for (int jb = blockIdx.x; jb < N_AGG; jb += gridDim.x) {
            const int n = jb * 4 + wv;
            const int d = min((int)deg[n], CAP);
            const size_t cbase = (size_t)n * CAP;

            int src0 = 0, src1 = 0;
            float w0 = 0.f, w1 = 0.f;
            if (lane < d)      { src0 = csr_src[cbase + lane];      w0 = es[src0]; }
            if (lane + 64 < d) { src1 = csr_src[cbase + lane + 64]; w1 = es[src1]; }
            float sum = w0 + w1;
#pragma unroll
            for (int o = 32; o > 0; o >>= 1) sum += __shfl_xor(sum, o);
            const float inv = 1.f / (sum + 1e-10f);

            float4 A0 = make_float4(0.f, 0.f, 0.f, 0.f), A1 = A0, A2 = A0, A3 = A0;
            {   // edges 0..min(d,64)
                const int cnt = min(d, 64);
                int e = 0;
                for (; e + 4 <= cnt; e += 4) {
                    const int s0 = __shfl(src0, e), s1 = __shfl(src0, e + 1);
                    const int s2 = __shfl(src0, e + 2), s3 = __shfl(src0, e + 3);
                    const float q0 = __shfl(w0, e),     q1 = __shfl(w0, e + 1);
                    const float q2 = __shfl(w0, e + 2), q3 = __shfl(w0, e + 3);
                    const ushort4 v0 = *(const ushort4*)&hb[(size_t)s0 * D + coff];
                    const ushort4 v1 = *(const ushort4*)&hb[(size_t)s1 * D + coff];
                    const ushort4 v2 = *(const ushort4*)&hb[(size_t)s2 * D + coff];
                    const ushort4 v3 = *(const ushort4*)&hb[(size_t)s3 * D + coff];
                    A0.x += q0 * bf2f(v0.x); A0.y += q0 * bf2f(v0.y); A0.z += q0 * bf2f(v0.z); A0.w += q0 * bf2f(v0.w);
                    A1.x += q1 * bf2f(v1.x); A1.y += q1 * bf2f(v1.y); A1.z += q1 * bf2f(v1.z); A1.w += q1 * bf2f(v1.w);
                    A2.x += q2 * bf2f(v2.x); A2.y += q2 * bf2f(v2.y); A2.z += q2 * bf2f(v2.z); A2.w += q2 * bf2f(v2.w);
                    A3.x += q3 * bf2f(v3.x); A3.y += q3 * bf2f(v3.y); A3.z += q3 * bf2f(v3.z); A3.w += q3 * bf2f(v3.w);
                }
                for (; e < cnt; ++e) {
                    const int s0 = __shfl(src0, e);
                    const float q0 = __shfl(w0, e);
                    const ushort4 v0 = *(const ushort4*)&hb[(size_t)s0 * D + coff];
                    A0.x += q0 * bf2f(v0.x); A0.y += q0 * bf2f(v0.y); A0.z += q0 * bf2f(v0.z); A0.w += q0 * bf2f(v0.w);
                }
            }
            if (d > 64) {   // edges 64..d
                const int cnt = d - 64;
                int e = 0;
                for (; e + 4 <= cnt; e += 4) {
                    const int s0 = __shfl(src1, e), s1 = __shfl(src1, e + 1);
                    const int s2 = __shfl(src1, e + 2), s3 = __shfl(src1, e + 3);
                    const float q0 = __shfl(w1, e),     q1 = __shfl(w1, e + 1);
                    const float q2 = __shfl(w1, e + 2), q3 = __shfl(w1, e + 3);
                    const ushort4 v0 = *(const ushort4*)&hb[(size_t)s0 * D + coff];
                    const ushort4 v1 = *(const ushort4*)&hb[(size_t)s1 * D + coff];
                    const ushort4 v2 = *(const ushort4*)&hb[(size_t)s2 * D + coff];
                    const ushort4 v3 = *(const ushort4*)&hb[(size_t)s3 * D + coff];
                    A0.x += q0 * bf2f(v0.x); A0.y += q0 * bf2f(v0.y); A0.z += q0 * bf2f(v0.z); A0.w += q0 * bf2f(v0.w);
                    A1.x += q1 * bf2f(v1.x); A1.y += q1 * bf2f(v1.y); A1.z += q1 * bf2f(v1.z); A1.w += q1 * bf2f(v1.w);
                    A2.x += q2 * bf2f(v2.x); A2.y += q2 * bf2f(v2.y); A2.z += q2 * bf2f(v2.z); A2.w += q2 * bf2f(v2.w);
                    A3.x += q3 * bf2f(v3.x); A3.y += q3 * bf2f(v3.y); A3.z += q3 * bf2f(v3.z); A3.w += q3 * bf2f(v3.w);
                }
                for (; e < cnt; ++e) {
                    const int s0 = __shfl(src1, e);
                    const float q0 = __shfl(w1, e);
                    const ushort4 v0 = *(const ushort4*)&hb[(size_t)s0 * D + coff];
                    A0.x += q0 * bf2f(v0.x); A0.y += q0 * bf2f(v0.y); A0.z += q0 * bf2f(v0.z); A0.w += q0 * bf2f(v0.w);
                }
            }
            float4 acc4 = make_float4((A0.x + A1.x + A2.x + A3.x) * inv,
                                      (A0.y + A1.y + A2.y + A3.y) * inv,
                                      (A0.z + A1.z + A2.z + A3.z) * inv,
                                      (A0.w + A1.w + A2.w + A3.w) * inv);

            const ushort4 hnv = *(const ushort4*)&hb[(size_t)n * D + coff];
            float4 u = make_float4(bf2f(hnv.x) + acc4.x, bf2f(hnv.y) + acc4.y,
                                   bf2f(hnv.z) + acc4.z, bf2f(hnv.w) + acc4.w);
            float ssq = u.x * u.x + u.y * u.y + u.z * u.z + u.w * u.w;
#pragma unroll
            for (int o = 32; o > 0; o >>= 1) ssq += __shfl_xor(ssq, o);
            const float un = sqrtf(ssq);
            const float un_c = fmaxf(un, 1e-15f);
            const float th = tanhf(un_c);
            float s = th / un_c;
            const float pn = th * (un / un_c);
            if (pn > 0.95f) s *= 0.95f / (pn + 1e-8f);
            float4 p = make_float4(u.x * s, u.y * s, u.z * s, u.w * s);
            *(float4*)&out[(size_t)n * D + coff] = p;
        }
    }
}

// ---------------- launch ----------------
extern "C" void kernel_launch(void* const* d_in, const int* in_sizes, int n_in,
                              void* d_out, int out_size, void* d_ws, size_t ws_size,
                              hipStream_t stream) {
    const float* x      = (const float*)d_in[0];
    const int*   ei     = (const int*)d_in[1];
    const float* W      = (const float*)d_in[2];
    const float* b      = (const float*)d_in[3];
    const float* mag_w  = (const float*)d_in[4];
    const float* mag_b  = (const float*)d_in[5];
    const float* attn_w = (const float*)d_in[6];
    float* out = (float*)d_out;

    char* ws = (char*)d_ws;
    ushort* hb = (ushort*)ws;         ws += (size_t)N_NODES * D * sizeof(ushort);
    float* es = (float*)ws;           ws += (size_t)N_NODES * sizeof(float);
    unsigned* deg = (unsigned*)ws;    ws += (size_t)N_NODES * sizeof(unsigned);
    int* csr_src = (int*)ws;          ws += (size_t)N_NODES * CAP * sizeof(int);
    ushort* Wb = (ushort*)ws;         ws += (size_t)D * D * sizeof(ushort);

    // size grid to guaranteed co-residency (cooperative launch requirement)
    int nb = 0;
    hipOccupancyMaxActiveBlocksPerMultiprocessor(&nb, k_all, 256, 0);
    if (nb < 1) nb = 1;
    long long grid = (long long)nb * 256;
    if (grid > 1024) grid = 1024;

    void* args[] = {(void*)&x, (void*)&ei, (void*)&W, (void*)&b, (void*)&mag_w,
                    (void*)&mag_b, (void*)&attn_w, (void*)&deg, (void*)&csr_src,
                    (void*)&hb, (void*)&es, (void*)&Wb, (void*)&out};
    hipLaunchCooperativeKernel((const void*)k_all, dim3((int)grid), dim3(256),
                               args, 0, stream);
}

// Round 6
// 57.633 us; speedup vs baseline: 3.2226x; 3.2226x over previous
//
#include <hip/hip_runtime.h>
#include <math.h>

#define N_NODES 10000
#define N_EDGES 320000
#define D 256
#define CAP 128   // per-node in-edge cap; deg ~ Poisson(32), P(>128) ~ 0
#define BM 32     // GEMM row-tile
#define LDK 40    // LDS k-stride in ushorts (80 B rows: 16B-aligned, bank-spread)
#define GB_GEMM ((N_NODES + BM - 1) / BM)      // 313
#define GB_BUILD ((N_EDGES + 255) / 256)       // 1250

typedef __attribute__((ext_vector_type(8))) short short8;
typedef __attribute__((ext_vector_type(4))) float f32x4;

__device__ __forceinline__ ushort f2bf(float f) {
    union { float f; unsigned u; } v; v.f = f;
    unsigned r = v.u + 0x7FFFu + ((v.u >> 16) & 1u);  // RNE
    return (ushort)(r >> 16);
}
__device__ __forceinline__ float bf2f(ushort u) {
    union { unsigned u; float f; } v; v.u = (unsigned)u << 16;
    return v.f;
}

// ---------------- K1: W fp32 -> bf16 + zero deg ----------------
__global__ __launch_bounds__(256) void k_prep(const float* __restrict__ W,
                                              ushort* __restrict__ Wb,
                                              unsigned* __restrict__ deg) {
    const int tid = blockIdx.x * 256 + threadIdx.x;
    const int i = tid * 4;
    const float4 v = *(const float4*)&W[i];
    ushort4 o;
    o.x = f2bf(v.x); o.y = f2bf(v.y); o.z = f2bf(v.z); o.w = f2bf(v.w);
    *(ushort4*)&Wb[i] = o;
    if (tid < N_NODES) deg[tid] = 0u;
}

// ---------------- K2 (fat): GEMM-fused (blocks < GB_GEMM) + edge scatter ----------------
// GEMM: 32 rows x 256 cols per block; 4 waves, wave w owns col strip [w*64,+64).
// Double-buffered LDS, 1 barrier/K-iter, loads for k+1 issued before MFMA of k.
// Epilogue: row norm + sigmoid magnitude -> hb (bf16), es = exp(h . a_s).
__global__ __launch_bounds__(256) void k_main(const float* __restrict__ x,
                                              const ushort* __restrict__ Wb,
                                              const float* __restrict__ b,
                                              const float* __restrict__ mag_w,
                                              const float* __restrict__ mag_b,
                                              const float* __restrict__ attn_w,
                                              const int* __restrict__ ei,
                                              unsigned* __restrict__ deg,
                                              int* __restrict__ csr_src,
                                              ushort* __restrict__ hb,
                                              float* __restrict__ es) {
    if (blockIdx.x >= GB_GEMM) {
        const int e = (blockIdx.x - GB_GEMM) * 256 + threadIdx.x;
        if (e < N_EDGES) {
            int src = ei[e];
            int tgt = ei[N_EDGES + e];
            src = min(max(src, 0), N_NODES - 1);
            tgt = min(max(tgt, 0), N_NODES - 1);
            const unsigned slot = atomicAdd(&deg[tgt], 1u);
            if (slot < CAP) csr_src[(size_t)tgt * CAP + slot] = src;
        }
        return;
    }

    __shared__ ushort ldsA[2][BM * LDK];
    __shared__ ushort ldsB[2][256 * LDK];
    __shared__ float red_ssq[4][BM], red_ra[4][BM];
    __shared__ float smrow[BM], scl[BM];

    const int t = threadIdx.x;
    const int w = t >> 6, l = t & 63;
    const int bm = blockIdx.x * BM;
    const int sra = t >> 3, ka = (t & 7) * 4;   // A staging: 8 thr/row x 4 floats
    const int am = bm + sra;
    const int srb = t >> 2, kb = (t & 3) * 8;   // B staging: 4 thr/row x 8 bf16
    const int fl = l & 15;
    const int fh = (l >> 4) * 8;
    const int rq = (l >> 4) * 4;

    f32x4 acc[2][4];
#pragma unroll
    for (int r = 0; r < 2; ++r)
#pragma unroll
        for (int c = 0; c < 4; ++c) acc[r][c] = (f32x4)(0.f);
    float sm_part = 0.f;

    float4 xa;
    short8 bv[4];

    // prologue: load k0 = 0
    {
        xa = make_float4(0.f, 0.f, 0.f, 0.f);
        if (am < N_NODES) xa = *(const float4*)&x[(size_t)am * D + ka];
        const float4 mwv = *(const float4*)&mag_w[ka];
        sm_part += xa.x * mwv.x + xa.y * mwv.y + xa.z * mwv.z + xa.w * mwv.w;
#pragma unroll
        for (int p = 0; p < 4; ++p)
            bv[p] = *(const short8*)&Wb[(size_t)(p * 64 + srb) * D + kb];
        ushort4 av;
        av.x = f2bf(xa.x); av.y = f2bf(xa.y); av.z = f2bf(xa.z); av.w = f2bf(xa.w);
        *(ushort4*)&ldsA[0][sra * LDK + ka] = av;
#pragma unroll
        for (int p = 0; p < 4; ++p)
            *(short8*)&ldsB[0][(p * 64 + srb) * LDK + kb] = bv[p];
    }
    __syncthreads();

    int cur = 0;
    for (int k0 = 32; k0 < D; k0 += 32) {
        // issue next tile's global loads (latency hides under MFMA below)
        xa = make_float4(0.f, 0.f, 0.f, 0.f);
        if (am < N_NODES) xa = *(const float4*)&x[(size_t)am * D + k0 + ka];
        const float4 mwv = *(const float4*)&mag_w[k0 + ka];
        sm_part += xa.x * mwv.x + xa.y * mwv.y + xa.z * mwv.z + xa.w * mwv.w;
#pragma unroll
        for (int p = 0; p < 4; ++p)
            bv[p] = *(const short8*)&Wb[(size_t)(p * 64 + srb) * D + k0 + kb];

        // compute on current buffer
        short8 af[2], bfr[4];
#pragma unroll
        for (int r = 0; r < 2; ++r)
            af[r] = *(short8*)&ldsA[cur][(r * 16 + fl) * LDK + fh];
#pragma unroll
        for (int c = 0; c < 4; ++c)
            bfr[c] = *(short8*)&ldsB[cur][(w * 64 + c * 16 + fl) * LDK + fh];
#pragma unroll
        for (int r = 0; r < 2; ++r)
#pragma unroll
            for (int c = 0; c < 4; ++c)
                acc[r][c] = __builtin_amdgcn_mfma_f32_16x16x32_bf16(af[r], bfr[c], acc[r][c], 0, 0, 0);

        // write next buffer (waits on the global loads), single barrier
        ushort4 av;
        av.x = f2bf(xa.x); av.y = f2bf(xa.y); av.z = f2bf(xa.z); av.w = f2bf(xa.w);
        *(ushort4*)&ldsA[cur ^ 1][sra * LDK + ka] = av;
#pragma unroll
        for (int p = 0; p < 4; ++p)
            *(short8*)&ldsB[cur ^ 1][(p * 64 + srb) * LDK + kb] = bv[p];
        __syncthreads();
        cur ^= 1;
    }
    // epilogue compute on last buffer
    {
        short8 af[2], bfr[4];
#pragma unroll
        for (int r = 0; r < 2; ++r)
            af[r] = *(short8*)&ldsA[cur][(r * 16 + fl) * LDK + fh];
#pragma unroll
        for (int c = 0; c < 4; ++c)
            bfr[c] = *(short8*)&ldsB[cur][(w * 64 + c * 16 + fl) * LDK + fh];
#pragma unroll
        for (int r = 0; r < 2; ++r)
#pragma unroll
            for (int c = 0; c < 4; ++c)
                acc[r][c] = __builtin_amdgcn_mfma_f32_16x16x32_bf16(af[r], bfr[c], acc[r][c], 0, 0, 0);
    }

    // mag dot: reduce across the 8 staging threads of each row
#pragma unroll
    for (int o = 1; o < 8; o <<= 1) sm_part += __shfl_xor(sm_part, o);
    if ((t & 7) == 0) smrow[sra] = sm_part;

    float bn[4], asn[4];
#pragma unroll
    for (int c = 0; c < 4; ++c) {
        const int n = w * 64 + c * 16 + fl;
        bn[c]  = b[n];
        asn[c] = attn_w[n];
    }

    // row reductions (ssq, h.a_s) within wave, then LDS cross-wave
#pragma unroll
    for (int r = 0; r < 2; ++r) {
#pragma unroll
        for (int reg = 0; reg < 4; ++reg) {
            float vssq = 0.f, vra = 0.f;
#pragma unroll
            for (int c = 0; c < 4; ++c) {
                const float v = acc[r][c][reg] + bn[c];
                vssq += v * v;
                vra  += v * asn[c];
            }
#pragma unroll
            for (int o = 1; o < 16; o <<= 1) {
                vssq += __shfl_xor(vssq, o);
                vra  += __shfl_xor(vra, o);
            }
            if (fl == 0) {
                const int m = r * 16 + rq + reg;
                red_ssq[w][m] = vssq;
                red_ra[w][m]  = vra;
            }
        }
    }
    __syncthreads();

    if (t < BM) {
        const int gm = bm + t;
        const float ssq = red_ssq[0][t] + red_ssq[1][t] + red_ssq[2][t] + red_ssq[3][t];
        const float ra  = red_ra[0][t]  + red_ra[1][t]  + red_ra[2][t]  + red_ra[3][t];
        const float norm = sqrtf(ssq);
        const float mag  = 1.5f / (1.f + expf(-(smrow[t] + mag_b[0])));
        const float scale = mag / fmaxf(norm, 1e-12f);
        scl[t] = scale;
        if (gm < N_NODES) es[gm] = expf(ra * scale);   // exp(s_s); |s_s| <= ~1.1
    }
    __syncthreads();

    // write hb = bf16(h_raw * scale)
#pragma unroll
    for (int r = 0; r < 2; ++r) {
#pragma unroll
        for (int reg = 0; reg < 4; ++reg) {
            const int ml = r * 16 + rq + reg;
            const int m = bm + ml;
            if (m < N_NODES) {
                const float scale = scl[ml];
#pragma unroll
                for (int c = 0; c < 4; ++c) {
                    const int n = w * 64 + c * 16 + fl;
                    hb[(size_t)m * D + n] = f2bf((acc[r][c][reg] + bn[c]) * scale);
                }
            }
        }
    }
}

// ---------------- K3: single-pass weighted gather + expmap0 + clip ----------------
// 1 wave per node, 4 nodes/block; no LDS/barriers. attn = es[src]/Σes[src]
// (s_t[tgt] cancels in segment softmax; |s_s|<=1.1 so max-shift unnecessary).
__global__ __launch_bounds__(256) void k_agg(const ushort* __restrict__ hb,
                                             const unsigned* __restrict__ deg,
                                             const int* __restrict__ csr_src,
                                             const float* __restrict__ es,
                                             float* __restrict__ out) {
    const int wv = threadIdx.x >> 6;
    const int n = blockIdx.x * 4 + wv;
    const int lane = threadIdx.x & 63;
    const int d = min((int)deg[n], CAP);
    const size_t cbase = (size_t)n * CAP;

    int src0 = 0, src1 = 0;
    float w0 = 0.f, w1 = 0.f;
    if (lane < d)      { src0 = csr_src[cbase + lane];      w0 = es[src0]; }
    if (lane + 64 < d) { src1 = csr_src[cbase + lane + 64]; w1 = es[src1]; }
    float sum = w0 + w1;
#pragma unroll
    for (int o = 32; o > 0; o >>= 1) sum += __shfl_xor(sum, o);
    const float inv = 1.f / (sum + 1e-10f);

    const int coff = lane * 4;
    float4 A0 = make_float4(0.f, 0.f, 0.f, 0.f), A1 = A0, A2 = A0, A3 = A0;

    {   // edges 0..min(d,64), 8-deep MLP
        const int cnt = min(d, 64);
        int e = 0;
        for (; e + 8 <= cnt; e += 8) {
            int s[8]; float q[8]; ushort4 v[8];
#pragma unroll
            for (int j = 0; j < 8; ++j) { s[j] = __shfl(src0, e + j); q[j] = __shfl(w0, e + j); }
#pragma unroll
            for (int j = 0; j < 8; ++j) v[j] = *(const ushort4*)&hb[(size_t)s[j] * D + coff];
#pragma unroll
            for (int j = 0; j < 8; ++j) {
                float4* A = (j & 2) ? ((j & 1) ? &A3 : &A2) : ((j & 1) ? &A1 : &A0);
                A->x += q[j] * bf2f(v[j].x); A->y += q[j] * bf2f(v[j].y);
                A->z += q[j] * bf2f(v[j].z); A->w += q[j] * bf2f(v[j].w);
            }
        }
        for (; e < cnt; ++e) {
            const int s0 = __shfl(src0, e);
            const float q0 = __shfl(w0, e);
            const ushort4 v0 = *(const ushort4*)&hb[(size_t)s0 * D + coff];
            A0.x += q0 * bf2f(v0.x); A0.y += q0 * bf2f(v0.y); A0.z += q0 * bf2f(v0.z); A0.w += q0 * bf2f(v0.w);
        }
    }
    if (d > 64) {   // edges 64..d
        const int cnt = d - 64;
        int e = 0;
        for (; e + 8 <= cnt; e += 8) {
            int s[8]; float q[8]; ushort4 v[8];
#pragma unroll
            for (int j = 0; j < 8; ++j) { s[j] = __shfl(src1, e + j); q[j] = __shfl(w1, e + j); }
#pragma unroll
            for (int j = 0; j < 8; ++j) v[j] = *(const ushort4*)&hb[(size_t)s[j] * D + coff];
#pragma unroll
            for (int j = 0; j < 8; ++j) {
                float4* A = (j & 2) ? ((j & 1) ? &A3 : &A2) : ((j & 1) ? &A1 : &A0);
                A->x += q[j] * bf2f(v[j].x); A->y += q[j] * bf2f(v[j].y);
                A->z += q[j] * bf2f(v[j].z); A->w += q[j] * bf2f(v[j].w);
            }
        }
        for (; e < cnt; ++e) {
            const int s0 = __shfl(src1, e);
            const float q0 = __shfl(w1, e);
            const ushort4 v0 = *(const ushort4*)&hb[(size_t)s0 * D + coff];
            A0.x += q0 * bf2f(v0.x); A0.y += q0 * bf2f(v0.y); A0.z += q0 * bf2f(v0.z); A0.w += q0 * bf2f(v0.w);
        }
    }
    float4 acc = make_float4((A0.x + A1.x + A2.x + A3.x) * inv,
                             (A0.y + A1.y + A2.y + A3.y) * inv,
                             (A0.z + A1.z + A2.z + A3.z) * inv,
                             (A0.w + A1.w + A2.w + A3.w) * inv);

    const ushort4 hnv = *(const ushort4*)&hb[(size_t)n * D + coff];
    float4 u = make_float4(bf2f(hnv.x) + acc.x, bf2f(hnv.y) + acc.y,
                           bf2f(hnv.z) + acc.z, bf2f(hnv.w) + acc.w);
    float ssq = u.x * u.x + u.y * u.y + u.z * u.z + u.w * u.w;
#pragma unroll
    for (int o = 32; o > 0; o >>= 1) ssq += __shfl_xor(ssq, o);
    const float un = sqrtf(ssq);
    const float un_c = fmaxf(un, 1e-15f);
    const float th = tanhf(un_c);
    float s = th / un_c;
    const float pn = th * (un / un_c);
    if (pn > 0.95f) s *= 0.95f / (pn + 1e-8f);
    float4 p = make_float4(u.x * s, u.y * s, u.z * s, u.w * s);
    *(float4*)&out[(size_t)n * D + coff] = p;
}

// ---------------- launch ----------------
extern "C" void kernel_launch(void* const* d_in, const int* in_sizes, int n_in,
                              void* d_out, int out_size, void* d_ws, size_t ws_size,
                              hipStream_t stream) {
    const float* x      = (const float*)d_in[0];
    const int*   ei     = (const int*)d_in[1];
    const float* W      = (const float*)d_in[2];
    const float* b      = (const float*)d_in[3];
    const float* mag_w  = (const float*)d_in[4];
    const float* mag_b  = (const float*)d_in[5];
    const float* attn_w = (const float*)d_in[6];
    float* out = (float*)d_out;

    char* ws = (char*)d_ws;
    ushort* hb = (ushort*)ws;         ws += (size_t)N_NODES * D * sizeof(ushort);
    float* es = (float*)ws;           ws += (size_t)N_NODES * sizeof(float);
    unsigned* deg = (unsigned*)ws;    ws += (size_t)N_NODES * sizeof(unsigned);
    int* csr_src = (int*)ws;          ws += (size_t)N_NODES * CAP * sizeof(int);
    ushort* Wb = (ushort*)ws;         ws += (size_t)D * D * sizeof(ushort);

    k_prep<<<(D * D) / (256 * 4), 256, 0, stream>>>(W, Wb, deg);
    k_main<<<GB_GEMM + GB_BUILD, 256, 0, stream>>>(
        x, Wb, b, mag_w, mag_b, attn_w, ei, deg, csr_src, hb, es);
    k_agg<<<N_NODES / 4, 256, 0, stream>>>(hb, deg, csr_src, es, out);
}